// Round 9
// baseline (345.595 us; speedup 1.0000x reference)
//
#include <hip/hip_runtime.h>
#include <hip/hip_bf16.h>
#include <stdint.h>

typedef __attribute__((ext_vector_type(8))) short short8;
typedef __attribute__((ext_vector_type(4))) short short4v;
typedef __attribute__((ext_vector_type(4))) float floatx4;

#define B_   16
#define N_   1024
#define C_   768
#define H_   12
#define D_   64
#define K_   768
// (1/sqrt(64)) * log2(e): folds softmax scale AND natural->base2 exp into Q
#define QSCALE 0.18033688011112042f

__device__ __forceinline__ short f2bf(float f) {
    __hip_bfloat16 h = __float2bfloat16(f);
    short s; __builtin_memcpy(&s, &h, 2); return s;
}
// packed 2xf32 -> 2xbf16 (v_cvt_pk_bf16_f32 on gfx950)
__device__ __forceinline__ unsigned pk2bf(float a, float b) {
    __hip_bfloat162 h = __float22bfloat162_rn(make_float2(a, b));
    unsigned u; __builtin_memcpy(&u, &h, 4); return u;
}

// async global->LDS DMA, 16 B per lane; LDS dest = wave-uniform base + lane*16
__device__ __forceinline__ void gl_lds16(const void* g, void* l) {
    __builtin_amdgcn_global_load_lds(
        (const __attribute__((address_space(1))) unsigned int*)g,
        (__attribute__((address_space(3))) unsigned int*)l, 16, 0, 0);
}

// LDS segment swizzle: seg' = seg ^ FSWZ(row).  Chosen so that for the attn
// fragment-read patterns (krow = cl*4+nt, vrow = dt*16+cl) consecutive lanes
// spread over all 8 segments (<=2-way aliasing, free per m136). Round 8's
// f=row&7 gave only 2 segs per 8 lanes -> 4-way -> 2.0e7 conflicts.
#define FSWZ(row) ((((row) >> 1) ^ ((row) >> 4)) & 7)

// ---------------------------------------------------------------------------
// fused fp32->bf16 for x, w_qkv, w_proj (ranges are 256-block aligned)
// ---------------------------------------------------------------------------
#define N8_X  1572864   // (16*1024*768)/8
#define N8_WQ 221184    // (2304*768)/8
#define N8_WP 73728     // (768*768)/8
__global__ void cvt_all(const float* __restrict__ x, const float* __restrict__ wq,
                        const float* __restrict__ wp, short* __restrict__ xb,
                        short* __restrict__ wqb, short* __restrict__ wpb)
{
    long i = (long)blockIdx.x * 256 + threadIdx.x;   // 8-elem units
    const float* src; short* dst;
    if (i < N8_X)              { src = x;  dst = xb;  }
    else if (i < N8_X + N8_WQ) { src = wq; dst = wqb; i -= N8_X; }
    else                       { src = wp; dst = wpb; i -= (long)N8_X + N8_WQ; }
    const float4* p = (const float4*)src + 2 * i;
    const float4 u = p[0], v = p[1];
    short8 r;
    r[0] = f2bf(u.x); r[1] = f2bf(u.y); r[2] = f2bf(u.z); r[3] = f2bf(u.w);
    r[4] = f2bf(v.x); r[5] = f2bf(v.y); r[6] = f2bf(v.z); r[7] = f2bf(v.w);
    *((short8*)dst + i) = r;
}

// ---------------------------------------------------------------------------
// GEMM  C[M,N] = A[M,K] * B[N,K]^T  (bf16, K-major, 128x128 tile, BK=32,
// global_load_lds staging — m97 structure).
// MODE 0: QKV epilogue -> q_ws [bh,n,d] (scaled), k_ws [bh,n,d], v_ws [bh,d,n]
// MODE 1: proj epilogue -> +bias, fp32 out
// ---------------------------------------------------------------------------
template<int MODE>
__global__ __launch_bounds__(256, 3)
void gemm_bt(const short* __restrict__ A, const short* __restrict__ Bm,
             const float* __restrict__ bias,
             short* __restrict__ q_ws, short* __restrict__ k_ws,
             short* __restrict__ v_ws, float* __restrict__ outp)
{
    __shared__ short Alds[128 * 32];
    __shared__ short Blds[128 * 32];
    const int tid  = threadIdx.x;
    const int wave = tid >> 6, lane = tid & 63;
    const int cl   = lane & 15, quad = lane >> 4;
    const int bm = blockIdx.x, bn = blockIdx.y;
    const int wm = (wave >> 1) * 64, wn = (wave & 1) * 64;

    const short* Ag = A  + (long)bm * 128 * K_ + (long)(tid >> 2) * K_ + (tid & 3) * 8;
    const short* Bg = Bm + (long)bn * 128 * K_ + (long)(tid >> 2) * K_ + (tid & 3) * 8;
    short* la = Alds + (tid & 0xC0) * 8;   // wave-uniform base
    short* lb = Blds + (tid & 0xC0) * 8;

    const floatx4 fzero = {0.f, 0.f, 0.f, 0.f};
    floatx4 acc[4][4];
    #pragma unroll
    for (int i = 0; i < 4; i++)
        #pragma unroll
        for (int j = 0; j < 4; j++) acc[i][j] = fzero;

    for (int kt = 0; kt < K_; kt += 32) {
        __syncthreads();                    // previous iter's readers done
        gl_lds16(Ag + kt,            la);
        gl_lds16(Ag + kt + 64 * K_,  la + 2048);
        gl_lds16(Bg + kt,            lb);
        gl_lds16(Bg + kt + 64 * K_,  lb + 2048);
        __syncthreads();                    // drains vmcnt (DMA complete)

        short8 af[4], bf[4];
        #pragma unroll
        for (int i = 0; i < 4; i++)
            af[i] = *(const short8*)(Alds + (wm + i * 16 + cl) * 32 + quad * 8);
        #pragma unroll
        for (int j = 0; j < 4; j++)
            bf[j] = *(const short8*)(Blds + (wn + j * 16 + cl) * 32 + quad * 8);
        #pragma unroll
        for (int i = 0; i < 4; i++)
            #pragma unroll
            for (int j = 0; j < 4; j++)
                acc[i][j] = __builtin_amdgcn_mfma_f32_16x16x32_bf16(af[i], bf[j], acc[i][j], 0, 0, 0);
    }

    // epilogue.  C/D layout: row(m) = quad*4 + reg, col(n) = cl  [m89/m91]
    #pragma unroll
    for (int i = 0; i < 4; i++) {
        const int gm0 = bm * 128 + wm + i * 16 + quad * 4;
        #pragma unroll
        for (int j = 0; j < 4; j++) {
            const int gn = bn * 128 + wn + j * 16 + cl;
            if (MODE == 0) {
                const int t   = bn / 6;          // 0=Q,1=K,2=V (block-uniform)
                const int rem = gn - t * 768;
                const int h   = rem >> 6, d = rem & 63;
                const int b   = gm0 >> 10;
                const int n0  = gm0 & 1023;
                const int bh  = b * H_ + h;
                if (t == 2) {
                    short4v pk;
                    #pragma unroll
                    for (int r = 0; r < 4; r++) pk[r] = f2bf(acc[i][j][r]);
                    *(short4v*)(v_ws + (((long)(bh * D_ + d)) << 10) + n0) = pk;   // [bh,d,n]
                } else {
                    short* dst = (t == 0) ? q_ws : k_ws;
                    const float sc = (t == 0) ? QSCALE : 1.0f;
                    #pragma unroll
                    for (int r = 0; r < 4; r++)
                        dst[((long)bh * N_ + (n0 + r)) * D_ + d] = f2bf(acc[i][j][r] * sc);
                }
            } else {
                const float bv = bias[gn];
                #pragma unroll
                for (int r = 0; r < 4; r++)
                    outp[(long)(gm0 + r) * C_ + gn] = acc[i][j][r] + bv;   // fp32 out
            }
        }
    }
}

// ---------------------------------------------------------------------------
// Flash attention v4: one block = one (b,h) x 128 Q-rows, 64-key chunks.
// Double-buffered 64x64 K/V tiles (1 barrier/chunk, loads overlap compute),
// FSWZ segment swizzle (<=2-way LDS aliasing on all access patterns),
// free key-permutation (S-col cl of tile nt <-> key cl*4+nt) so P-pack is a
// contiguous 8B write; V stays in natural [d][n] order. LDS 41 KB -> 3 blk/CU
// (L2-safe: 12 resident bh/XCD = 3 MB KV <= 4 MB L2; 6 blk/CU thrashed, r7).
// ---------------------------------------------------------------------------
__global__ __launch_bounds__(256, 3)
void attn_fused(const short* __restrict__ q_ws, const short* __restrict__ k_ws,
                const short* __restrict__ v_ws, short* __restrict__ o_ws)
{
    __shared__ short Klds[2][64 * 64];    // [buf][key][d]
    __shared__ short Vlds[2][64 * 64];    // [buf][d][key]
    __shared__ short Plds[4][16 * 72];    // per-wave [qrow][key], pad 64->72

    const int tid  = threadIdx.x;
    const int wave = tid >> 6, lane = tid & 63;
    const int cl   = lane & 15, quad = lane >> 4;

    // XCD swizzle: each XCD owns 24 bh, qt-minor
    const int linear = blockIdx.y * 8 + blockIdx.x;   // gridDim = (8, 192)
    const int xcd = linear & 7, slot = linear >> 3;
    const int bh  = xcd * 24 + (slot >> 3);
    const int qt  = slot & 7;

    const long base = (long)bh * (N_ * D_);
    const int  qr0  = qt * 128 + wave * 32 + cl;

    short8 qf[2][2];
    #pragma unroll
    for (int mt = 0; mt < 2; mt++) {
        qf[mt][0] = *(const short8*)(q_ws + base + (long)(qr0 + mt * 16) * D_ + quad * 8);
        qf[mt][1] = *(const short8*)(q_ws + base + (long)(qr0 + mt * 16) * D_ + 32 + quad * 8);
    }

    const floatx4 fzero = {0.f, 0.f, 0.f, 0.f};
    float m_r[2][4], l_r[2][4];
    floatx4 o_acc[2][4];
    #pragma unroll
    for (int mt = 0; mt < 2; mt++)
        #pragma unroll
        for (int r = 0; r < 4; r++) {
            m_r[mt][r] = -1e30f; l_r[mt][r] = 0.f; o_acc[mt][r] = fzero;
        }

    const int srow = tid >> 2;          // 0..63: key row (K) / d row (V)
    const int sg0  = (tid & 3) * 2;     // first of two 8-short segments
    const int xw   = FSWZ(srow);        // write-side swizzle
    short* pl = &Plds[wave][0];

    // prologue: stage chunk 0 into buffer 0
    {
        short8 k0 = *(const short8*)(k_ws + base + (long)srow * D_ + sg0 * 8);
        short8 k1 = *(const short8*)(k_ws + base + (long)srow * D_ + sg0 * 8 + 8);
        short8 v0 = *(const short8*)(v_ws + base + (long)srow * N_ + sg0 * 8);
        short8 v1 = *(const short8*)(v_ws + base + (long)srow * N_ + sg0 * 8 + 8);
        *(short8*)(&Klds[0][0] + srow * 64 + ((sg0    ) ^ xw) * 8) = k0;
        *(short8*)(&Klds[0][0] + srow * 64 + ((sg0 + 1) ^ xw) * 8) = k1;
        *(short8*)(&Vlds[0][0] + srow * 64 + ((sg0    ) ^ xw) * 8) = v0;
        *(short8*)(&Vlds[0][0] + srow * 64 + ((sg0 + 1) ^ xw) * 8) = v1;
    }
    __syncthreads();

    for (int kc = 0; kc < N_; kc += 64) {
        const int cb = (kc >> 6) & 1;
        const int kn = kc + 64;
        short8 nk0, nk1, nv0, nv1;
        if (kn < N_) {   // issue next chunk's loads before compute (latency hiding)
            nk0 = *(const short8*)(k_ws + base + (long)(kn + srow) * D_ + sg0 * 8);
            nk1 = *(const short8*)(k_ws + base + (long)(kn + srow) * D_ + sg0 * 8 + 8);
            nv0 = *(const short8*)(v_ws + base + (long)srow * N_ + kn + sg0 * 8);
            nv1 = *(const short8*)(v_ws + base + (long)srow * N_ + kn + sg0 * 8 + 8);
        }
        const short* Kc = &Klds[cb][0];
        const short* Vc = &Vlds[cb][0];

        #pragma unroll
        for (int mt = 0; mt < 2; mt++) {
            // S = Q*K^T; tile nt: S-col cl <-> key cl*4+nt (free permutation)
            floatx4 s[4];
            #pragma unroll
            for (int nt = 0; nt < 4; nt++) {
                const int krow = cl * 4 + nt;
                const int xr   = FSWZ(krow);
                const short* kr = Kc + krow * 64;
                short8 kf0 = *(const short8*)(kr + ((quad    ) ^ xr) * 8);
                short8 kf1 = *(const short8*)(kr + ((quad + 4) ^ xr) * 8);
                floatx4 t4 = fzero;
                t4 = __builtin_amdgcn_mfma_f32_16x16x32_bf16(qf[mt][0], kf0, t4, 0, 0, 0);
                t4 = __builtin_amdgcn_mfma_f32_16x16x32_bf16(qf[mt][1], kf1, t4, 0, 0, 0);
                s[nt] = t4;
            }

            // online softmax; rows = quad*4 + r (max/sum key-order-invariant)
            float alpha[4];
            #pragma unroll
            for (int r = 0; r < 4; r++) {
                float v = fmaxf(fmaxf(s[0][r], s[1][r]), fmaxf(s[2][r], s[3][r]));
                v = fmaxf(v, __shfl_xor(v, 1));
                v = fmaxf(v, __shfl_xor(v, 2));
                v = fmaxf(v, __shfl_xor(v, 4));
                v = fmaxf(v, __shfl_xor(v, 8));
                const float mn = fmaxf(m_r[mt][r], v);
                alpha[r] = __builtin_amdgcn_exp2f(m_r[mt][r] - mn);
                m_r[mt][r] = mn;
                l_r[mt][r] *= alpha[r];
            }
            // P: lane's 4 values per row are keys cl*4..cl*4+3 -> contiguous 8B
            #pragma unroll
            for (int r = 0; r < 4; r++) {
                float p0 = __builtin_amdgcn_exp2f(s[0][r] - m_r[mt][r]);
                float p1 = __builtin_amdgcn_exp2f(s[1][r] - m_r[mt][r]);
                float p2 = __builtin_amdgcn_exp2f(s[2][r] - m_r[mt][r]);
                float p3 = __builtin_amdgcn_exp2f(s[3][r] - m_r[mt][r]);
                l_r[mt][r] += (p0 + p1) + (p2 + p3);
                uint2 pk = { pk2bf(p0, p1), pk2bf(p2, p3) };
                *(uint2*)(pl + (quad * 4 + r) * 72 + cl * 4) = pk;
            }
            #pragma unroll
            for (int dt = 0; dt < 4; dt++) {
                o_acc[mt][dt][0] *= alpha[0]; o_acc[mt][dt][1] *= alpha[1];
                o_acc[mt][dt][2] *= alpha[2]; o_acc[mt][dt][3] *= alpha[3];
            }
            asm volatile("" ::: "memory");   // order P writes before P reads

            // O += P*V: A=P [m=cl][k=key], B=V [n=d][k=key] (natural order)
            #pragma unroll
            for (int ks = 0; ks < 2; ks++) {
                short8 pf = *(const short8*)(pl + cl * 72 + ks * 32 + quad * 8);
                #pragma unroll
                for (int dt = 0; dt < 4; dt++) {
                    const int vrow = dt * 16 + cl;
                    const int xr   = FSWZ(vrow);
                    const short* vr = Vc + vrow * 64;
                    short8 vf = *(const short8*)(vr + ((ks * 4 + quad) ^ xr) * 8);
                    o_acc[mt][dt] = __builtin_amdgcn_mfma_f32_16x16x32_bf16(pf, vf, o_acc[mt][dt], 0, 0, 0);
                }
            }
            asm volatile("" ::: "memory");   // P reads done before next mt's writes
        }

        if (kn < N_) {   // write staged regs into the other buffer
            short* Kn = &Klds[cb ^ 1][0];
            short* Vn = &Vlds[cb ^ 1][0];
            *(short8*)(Kn + srow * 64 + ((sg0    ) ^ xw) * 8) = nk0;
            *(short8*)(Kn + srow * 64 + ((sg0 + 1) ^ xw) * 8) = nk1;
            *(short8*)(Vn + srow * 64 + ((sg0    ) ^ xw) * 8) = nv0;
            *(short8*)(Vn + srow * 64 + ((sg0 + 1) ^ xw) * 8) = nv1;
        }
        __syncthreads();   // single barrier per chunk (dbuf)
    }

    // finalize: reduce l across the quad's 16 lanes, normalize, store [b,n,c]
    const int b = bh / H_, h = bh - b * H_;
    #pragma unroll
    for (int mt = 0; mt < 2; mt++) {
        #pragma unroll
        for (int r = 0; r < 4; r++) {
            float v = l_r[mt][r];
            v += __shfl_xor(v, 1); v += __shfl_xor(v, 2);
            v += __shfl_xor(v, 4); v += __shfl_xor(v, 8);
            l_r[mt][r] = 1.0f / v;
        }
        const int nrow = qt * 128 + wave * 32 + mt * 16 + quad * 4;
        #pragma unroll
        for (int dt = 0; dt < 4; dt++) {
            const int c = h * D_ + dt * 16 + cl;
            #pragma unroll
            for (int r = 0; r < 4; r++)
                o_ws[((long)(b * N_ + nrow + r)) * C_ + c] = f2bf(o_acc[mt][dt][r] * l_r[mt][r]);
        }
    }
}

extern "C" void kernel_launch(void* const* d_in, const int* in_sizes, int n_in,
                              void* d_out, int out_size, void* d_ws, size_t ws_size,
                              hipStream_t stream)
{
    const float* x      = (const float*)d_in[0];
    const float* w_qkv  = (const float*)d_in[1];
    const float* w_proj = (const float*)d_in[2];
    const float* b_proj = (const float*)d_in[3];
    float* out = (float*)d_out;

    const long SZ = (long)B_ * N_ * C_;
    short* q_ws   = (short*)d_ws;                  // [bh, n, d] (pre-scaled)
    short* k_ws   = q_ws + SZ;                     // [bh, n, d]
    short* v_ws   = k_ws + SZ;                     // [bh, d, n]
    short* x_bf   = v_ws + SZ;                     // x as bf16; reused as o_ws
    short* o_ws   = x_bf;                          // alias: x dead after QKV GEMM
    short* wqkv_bf  = x_bf + SZ;
    short* wproj_bf = wqkv_bf + (long)3 * C_ * C_;

    cvt_all<<<dim3(7296), 256, 0, stream>>>(x, w_qkv, w_proj, x_bf, wqkv_bf, wproj_bf);
    gemm_bt<0><<<dim3(128, 18), 256, 0, stream>>>(x_bf, wqkv_bf, nullptr, q_ws, k_ws, v_ws, nullptr);
    attn_fused<<<dim3(8, 192), 256, 0, stream>>>(q_ws, k_ws, v_ws, o_ws);
    gemm_bt<1><<<dim3(128, 6), 256, 0, stream>>>(o_ws, wproj_bf, b_proj, nullptr, nullptr, nullptr, out);
}

// Round 10
// 304.114 us; speedup vs baseline: 1.1364x; 1.1364x over previous
//
#include <hip/hip_runtime.h>
#include <hip/hip_bf16.h>
#include <stdint.h>

typedef __attribute__((ext_vector_type(8))) short short8;
typedef __attribute__((ext_vector_type(4))) short short4v;
typedef __attribute__((ext_vector_type(4))) float floatx4;

#define B_   16
#define N_   1024
#define C_   768
#define H_   12
#define D_   64
#define K_   768
// (1/sqrt(64)) * log2(e): folds softmax scale AND natural->base2 exp into Q
#define QSCALE 0.18033688011112042f

__device__ __forceinline__ short f2bf(float f) {
    __hip_bfloat16 h = __float2bfloat16(f);
    short s; __builtin_memcpy(&s, &h, 2); return s;
}
// packed 2xf32 -> 2xbf16 (v_cvt_pk_bf16_f32 on gfx950)
__device__ __forceinline__ unsigned pk2bf(float a, float b) {
    __hip_bfloat162 h = __float22bfloat162_rn(make_float2(a, b));
    unsigned u; __builtin_memcpy(&u, &h, 4); return u;
}

// async global->LDS DMA, 16 B per lane; LDS dest = wave-uniform base + lane*16
__device__ __forceinline__ void gl_lds16(const void* g, void* l) {
    __builtin_amdgcn_global_load_lds(
        (const __attribute__((address_space(1))) unsigned int*)g,
        (__attribute__((address_space(3))) unsigned int*)l, 16, 0, 0);
}

// ---------------------------------------------------------------------------
// fused fp32->bf16 for x, w_qkv, w_proj (ranges are 256-block aligned)
// ---------------------------------------------------------------------------
#define N8_X  1572864   // (16*1024*768)/8
#define N8_WQ 221184    // (2304*768)/8
#define N8_WP 73728     // (768*768)/8
__global__ void cvt_all(const float* __restrict__ x, const float* __restrict__ wq,
                        const float* __restrict__ wp, short* __restrict__ xb,
                        short* __restrict__ wqb, short* __restrict__ wpb)
{
    long i = (long)blockIdx.x * 256 + threadIdx.x;   // 8-elem units
    const float* src; short* dst;
    if (i < N8_X)              { src = x;  dst = xb;  }
    else if (i < N8_X + N8_WQ) { src = wq; dst = wqb; i -= N8_X; }
    else                       { src = wp; dst = wpb; i -= (long)N8_X + N8_WQ; }
    const float4* p = (const float4*)src + 2 * i;
    const float4 u = p[0], v = p[1];
    short8 r;
    r[0] = f2bf(u.x); r[1] = f2bf(u.y); r[2] = f2bf(u.z); r[3] = f2bf(u.w);
    r[4] = f2bf(v.x); r[5] = f2bf(v.y); r[6] = f2bf(v.z); r[7] = f2bf(v.w);
    *((short8*)dst + i) = r;
}

// ---------------------------------------------------------------------------
// GEMM  C[M,N] = A[M,K] * B[N,K]^T  (bf16, K-major, 128x128 tile, BK=32,
// global_load_lds staging — m97 structure).
// MODE 0: QKV epilogue -> q_ws [bh,n,d] (scaled), k_ws [bh,n,d], v_ws [bh,d,n]
// MODE 1: proj epilogue -> +bias, fp32 out
// ---------------------------------------------------------------------------
template<int MODE>
__global__ __launch_bounds__(256, 3)
void gemm_bt(const short* __restrict__ A, const short* __restrict__ Bm,
             const float* __restrict__ bias,
             short* __restrict__ q_ws, short* __restrict__ k_ws,
             short* __restrict__ v_ws, float* __restrict__ outp)
{
    __shared__ short Alds[128 * 32];
    __shared__ short Blds[128 * 32];
    const int tid  = threadIdx.x;
    const int wave = tid >> 6, lane = tid & 63;
    const int cl   = lane & 15, quad = lane >> 4;
    const int bm = blockIdx.x, bn = blockIdx.y;
    const int wm = (wave >> 1) * 64, wn = (wave & 1) * 64;

    const short* Ag = A  + (long)bm * 128 * K_ + (long)(tid >> 2) * K_ + (tid & 3) * 8;
    const short* Bg = Bm + (long)bn * 128 * K_ + (long)(tid >> 2) * K_ + (tid & 3) * 8;
    short* la = Alds + (tid & 0xC0) * 8;   // wave-uniform base
    short* lb = Blds + (tid & 0xC0) * 8;

    const floatx4 fzero = {0.f, 0.f, 0.f, 0.f};
    floatx4 acc[4][4];
    #pragma unroll
    for (int i = 0; i < 4; i++)
        #pragma unroll
        for (int j = 0; j < 4; j++) acc[i][j] = fzero;

    for (int kt = 0; kt < K_; kt += 32) {
        __syncthreads();                    // previous iter's readers done
        gl_lds16(Ag + kt,            la);
        gl_lds16(Ag + kt + 64 * K_,  la + 2048);
        gl_lds16(Bg + kt,            lb);
        gl_lds16(Bg + kt + 64 * K_,  lb + 2048);
        __syncthreads();                    // drains vmcnt (DMA complete)

        short8 af[4], bf[4];
        #pragma unroll
        for (int i = 0; i < 4; i++)
            af[i] = *(const short8*)(Alds + (wm + i * 16 + cl) * 32 + quad * 8);
        #pragma unroll
        for (int j = 0; j < 4; j++)
            bf[j] = *(const short8*)(Blds + (wn + j * 16 + cl) * 32 + quad * 8);
        #pragma unroll
        for (int i = 0; i < 4; i++)
            #pragma unroll
            for (int j = 0; j < 4; j++)
                acc[i][j] = __builtin_amdgcn_mfma_f32_16x16x32_bf16(af[i], bf[j], acc[i][j], 0, 0, 0);
    }

    // epilogue.  C/D layout: row(m) = quad*4 + reg, col(n) = cl  [m89/m91]
    #pragma unroll
    for (int i = 0; i < 4; i++) {
        const int gm0 = bm * 128 + wm + i * 16 + quad * 4;
        #pragma unroll
        for (int j = 0; j < 4; j++) {
            const int gn = bn * 128 + wn + j * 16 + cl;
            if (MODE == 0) {
                const int t   = bn / 6;          // 0=Q,1=K,2=V (block-uniform)
                const int rem = gn - t * 768;
                const int h   = rem >> 6, d = rem & 63;
                const int b   = gm0 >> 10;
                const int n0  = gm0 & 1023;
                const int bh  = b * H_ + h;
                if (t == 2) {
                    short4v pk;
                    #pragma unroll
                    for (int r = 0; r < 4; r++) pk[r] = f2bf(acc[i][j][r]);
                    *(short4v*)(v_ws + (((long)(bh * D_ + d)) << 10) + n0) = pk;   // [bh,d,n]
                } else {
                    short* dst = (t == 0) ? q_ws : k_ws;
                    const float sc = (t == 0) ? QSCALE : 1.0f;
                    #pragma unroll
                    for (int r = 0; r < 4; r++)
                        dst[((long)bh * N_ + (n0 + r)) * D_ + d] = f2bf(acc[i][j][r] * sc);
                }
            } else {
                const float bv = bias[gn];
                #pragma unroll
                for (int r = 0; r < 4; r++)
                    outp[(long)(gm0 + r) * C_ + gn] = acc[i][j][r] + bv;   // fp32 out
            }
        }
    }
}

// ---------------------------------------------------------------------------
// Flash attention v5: one block = one (b,h) x 128 Q-rows, 128-key chunks.
// LDS-op-minimized: K-fragment reads SHARED across both m-tiles (S for both
// computed in one nt loop), so per chunk per wave: 16 K-reads + 32 V-reads +
// 8 P-writes + 8 P-reads + 8 staging writes (vs 88 in v4), 2 barriers.
// Per-array exact swizzles (all b128 accesses hit 8 distinct bank-groups per
// 8-lane cycle group — b128 grouping, NOT wave64-b32; 2-way halves b128 rate):
//   K [128][64]: f(row)=((row>>3)^(row&7))&7, read rows krow=cl*8+nt
//   V [64][128]: f(row)=row&7 (natural key order), read rows dt*16+cl
//   P [16][136]: stride-17-seg layout, rows cl*8 -> contiguous-key b128 writes
// LDS 49 KB -> 3 blocks/CU (L2-safe: 12 resident bh/XCD = 3 MB <= 4 MB L2).
// ---------------------------------------------------------------------------
__global__ __launch_bounds__(256, 3)
void attn_fused(const short* __restrict__ q_ws, const short* __restrict__ k_ws,
                const short* __restrict__ v_ws, short* __restrict__ o_ws)
{
    __shared__ short Klds[128 * 64];      // [key][d], swizzled segs
    __shared__ short Vlds[64 * 128];      // [d][key], swizzled segs
    __shared__ short Plds[4][16 * 136];   // per-wave [qrow][key], pad 128->136

    const int tid  = threadIdx.x;
    const int wave = tid >> 6, lane = tid & 63;
    const int cl   = lane & 15, quad = lane >> 4;

    // XCD swizzle: each XCD owns 24 bh, qt-minor
    const int linear = blockIdx.y * 8 + blockIdx.x;   // gridDim = (8, 192)
    const int xcd = linear & 7, slot = linear >> 3;
    const int bh  = xcd * 24 + (slot >> 3);
    const int qt  = slot & 7;

    const long base = (long)bh * (N_ * D_);
    const int  qr0  = qt * 128 + wave * 32 + cl;

    short8 qf[2][2];
    #pragma unroll
    for (int mt = 0; mt < 2; mt++) {
        qf[mt][0] = *(const short8*)(q_ws + base + (long)(qr0 + mt * 16) * D_ + quad * 8);
        qf[mt][1] = *(const short8*)(q_ws + base + (long)(qr0 + mt * 16) * D_ + 32 + quad * 8);
    }

    const floatx4 fzero = {0.f, 0.f, 0.f, 0.f};
    float m_r[2][4], l_r[2][4];
    floatx4 o_acc[2][4];
    #pragma unroll
    for (int mt = 0; mt < 2; mt++)
        #pragma unroll
        for (int r = 0; r < 4; r++) {
            m_r[mt][r] = -1e30f; l_r[mt][r] = 0.f; o_acc[mt][r] = fzero;
        }

    const int skey = tid >> 3, sseg = tid & 7;    // K staging: 32 rows/pass, 8 segs
    const int vd   = tid >> 4, vseg = tid & 15;   // V staging: 16 rows/pass, 16 segs
    short* pl = &Plds[wave][0];

    for (int kc = 0; kc < N_; kc += 128) {
        short8 kst[4], vst[4];
        #pragma unroll
        for (int p = 0; p < 4; p++) {
            kst[p] = *(const short8*)(k_ws + base + (long)(kc + p * 32 + skey) * D_ + sseg * 8);
            vst[p] = *(const short8*)(v_ws + base + (long)(p * 16 + vd) * N_ + kc + vseg * 8);
        }
        __syncthreads();
        #pragma unroll
        for (int p = 0; p < 4; p++) {
            const int krow = p * 32 + skey;
            const int fk   = ((krow >> 3) ^ (krow & 7)) & 7;
            *(short8*)(Klds + krow * 64 + (sseg ^ fk) * 8) = kst[p];
            const int vrow = p * 16 + vd;
            *(short8*)(Vlds + vrow * 128 + (vseg ^ (vrow & 7)) * 8) = vst[p];
        }
        __syncthreads();

        // QK^T for BOTH m-tiles with one K-fragment read per nt.
        // Tile nt: S-col cl <-> key cl*8+nt (free permutation; lane's 8 keys
        // across nt are contiguous cl*8..cl*8+7).
        floatx4 s[2][8];
        #pragma unroll
        for (int nt = 0; nt < 8; nt++) {
            const int krow = cl * 8 + nt;
            const int fk   = ((krow >> 3) ^ (krow & 7)) & 7;   // = (cl^nt)&7
            const short* kr = Klds + krow * 64;
            short8 kf0 = *(const short8*)(kr + ((quad    ) ^ fk) * 8);
            short8 kf1 = *(const short8*)(kr + ((quad + 4) ^ fk) * 8);
            floatx4 t0 = fzero, t1 = fzero;
            t0 = __builtin_amdgcn_mfma_f32_16x16x32_bf16(qf[0][0], kf0, t0, 0, 0, 0);
            t0 = __builtin_amdgcn_mfma_f32_16x16x32_bf16(qf[0][1], kf1, t0, 0, 0, 0);
            t1 = __builtin_amdgcn_mfma_f32_16x16x32_bf16(qf[1][0], kf0, t1, 0, 0, 0);
            t1 = __builtin_amdgcn_mfma_f32_16x16x32_bf16(qf[1][1], kf1, t1, 0, 0, 0);
            s[0][nt] = t0; s[1][nt] = t1;
        }

        #pragma unroll
        for (int mt = 0; mt < 2; mt++) {
            // online softmax; rows = quad*4 + r (key-order-invariant)
            float alpha[4];
            #pragma unroll
            for (int r = 0; r < 4; r++) {
                float v = fmaxf(fmaxf(s[mt][0][r], s[mt][1][r]), fmaxf(s[mt][2][r], s[mt][3][r]));
                v = fmaxf(v, fmaxf(fmaxf(s[mt][4][r], s[mt][5][r]), fmaxf(s[mt][6][r], s[mt][7][r])));
                v = fmaxf(v, __shfl_xor(v, 1));
                v = fmaxf(v, __shfl_xor(v, 2));
                v = fmaxf(v, __shfl_xor(v, 4));
                v = fmaxf(v, __shfl_xor(v, 8));
                const float mn = fmaxf(m_r[mt][r], v);
                alpha[r] = __builtin_amdgcn_exp2f(m_r[mt][r] - mn);
                m_r[mt][r] = mn;
                l_r[mt][r] *= alpha[r];
            }
            // P: lane's 8 values per row are keys cl*8..cl*8+7 -> one b128 write
            #pragma unroll
            for (int r = 0; r < 4; r++) {
                float p0 = __builtin_amdgcn_exp2f(s[mt][0][r] - m_r[mt][r]);
                float p1 = __builtin_amdgcn_exp2f(s[mt][1][r] - m_r[mt][r]);
                float p2 = __builtin_amdgcn_exp2f(s[mt][2][r] - m_r[mt][r]);
                float p3 = __builtin_amdgcn_exp2f(s[mt][3][r] - m_r[mt][r]);
                float p4 = __builtin_amdgcn_exp2f(s[mt][4][r] - m_r[mt][r]);
                float p5 = __builtin_amdgcn_exp2f(s[mt][5][r] - m_r[mt][r]);
                float p6 = __builtin_amdgcn_exp2f(s[mt][6][r] - m_r[mt][r]);
                float p7 = __builtin_amdgcn_exp2f(s[mt][7][r] - m_r[mt][r]);
                l_r[mt][r] += ((p0 + p1) + (p2 + p3)) + ((p4 + p5) + (p6 + p7));
                uint4 pk = { pk2bf(p0, p1), pk2bf(p2, p3), pk2bf(p4, p5), pk2bf(p6, p7) };
                *(uint4*)(pl + (quad * 4 + r) * 136 + cl * 8) = pk;
            }
            #pragma unroll
            for (int dt = 0; dt < 4; dt++) {
                o_acc[mt][dt][0] *= alpha[0]; o_acc[mt][dt][1] *= alpha[1];
                o_acc[mt][dt][2] *= alpha[2]; o_acc[mt][dt][3] *= alpha[3];
            }
            asm volatile("" ::: "memory");   // order P writes before P reads

            // O += P*V: A=P [m=cl][k=key], B=V [n=d][k=key]
            #pragma unroll
            for (int ks = 0; ks < 4; ks++) {
                short8 pf = *(const short8*)(pl + cl * 136 + ks * 32 + quad * 8);
                #pragma unroll
                for (int dt = 0; dt < 4; dt++) {
                    const int vrow = dt * 16 + cl;
                    const short* vr = Vlds + vrow * 128;
                    short8 vf = *(const short8*)(vr + ((ks * 4 + quad) ^ (vrow & 7)) * 8);
                    o_acc[mt][dt] = __builtin_amdgcn_mfma_f32_16x16x32_bf16(pf, vf, o_acc[mt][dt], 0, 0, 0);
                }
            }
            asm volatile("" ::: "memory");   // P reads done before next mt's writes
        }
    }

    // finalize: reduce l across the quad's 16 lanes, normalize, store [b,n,c]
    const int b = bh / H_, h = bh - b * H_;
    #pragma unroll
    for (int mt = 0; mt < 2; mt++) {
        #pragma unroll
        for (int r = 0; r < 4; r++) {
            float v = l_r[mt][r];
            v += __shfl_xor(v, 1); v += __shfl_xor(v, 2);
            v += __shfl_xor(v, 4); v += __shfl_xor(v, 8);
            l_r[mt][r] = 1.0f / v;
        }
        const int nrow = qt * 128 + wave * 32 + mt * 16 + quad * 4;
        #pragma unroll
        for (int dt = 0; dt < 4; dt++) {
            const int c = h * D_ + dt * 16 + cl;
            #pragma unroll
            for (int r = 0; r < 4; r++)
                o_ws[((long)(b * N_ + nrow + r)) * C_ + c] = f2bf(o_acc[mt][dt][r] * l_r[mt][r]);
        }
    }
}

extern "C" void kernel_launch(void* const* d_in, const int* in_sizes, int n_in,
                              void* d_out, int out_size, void* d_ws, size_t ws_size,
                              hipStream_t stream)
{
    const float* x      = (const float*)d_in[0];
    const float* w_qkv  = (const float*)d_in[1];
    const float* w_proj = (const float*)d_in[2];
    const float* b_proj = (const float*)d_in[3];
    float* out = (float*)d_out;

    const long SZ = (long)B_ * N_ * C_;
    short* q_ws   = (short*)d_ws;                  // [bh, n, d] (pre-scaled)
    short* k_ws   = q_ws + SZ;                     // [bh, n, d]
    short* v_ws   = k_ws + SZ;                     // [bh, d, n]
    short* x_bf   = v_ws + SZ;                     // x as bf16; reused as o_ws
    short* o_ws   = x_bf;                          // alias: x dead after QKV GEMM
    short* wqkv_bf  = x_bf + SZ;
    short* wproj_bf = wqkv_bf + (long)3 * C_ * C_;

    cvt_all<<<dim3(7296), 256, 0, stream>>>(x, w_qkv, w_proj, x_bf, wqkv_bf, wproj_bf);
    gemm_bt<0><<<dim3(128, 18), 256, 0, stream>>>(x_bf, wqkv_bf, nullptr, q_ws, k_ws, v_ws, nullptr);
    attn_fused<<<dim3(8, 192), 256, 0, stream>>>(q_ws, k_ws, v_ws, o_ws);
    gemm_bt<1><<<dim3(128, 6), 256, 0, stream>>>(o_ws, wproj_bf, b_proj, nullptr, nullptr, nullptr, out);
}